// Round 3
// baseline (502.076 us; speedup 1.0000x reference)
//
#include <hip/hip_runtime.h>

// ============================================================================
// t3 recurrence via affine-operator doubling + bf16x3 split MFMA GEMMs.
//
// Reference: t3=t1; repeat 50x { t3 = t1 + t2@t3; t3 = t1 + t3@t2 }; out=t3+t1
// Fused step: t3 <- C + t2 @ t3 @ t2,  C = t1 + t1@t2
// Operator F=(S,P): X -> S + P X P.  All P are powers of t2 (commute).
//   double:  S2k = Sk + Pk Sk Pk (2 mm), P2k = Pk Pk (1 mm)
//   compose: S(a+b) = Sa + Pa Sb Pa,  P(a+b) = Pa Pb
// Schedule: S1=C; double to F^16; X2=F^2(t1); compose F^32, F^48;
//           out = F^48(X2) + t1.   23 matmuls in 14 launches.
//
// R3: 16x16x32 MFMA + 4x2 register blocking (0.5 KB LDS/MFMA vs 0.67),
//     XOR-swizzled LDS (conflict-free ds_read_b128/ds_write_b128),
//     2D XCD block swizzle for L2 reuse.
// ============================================================================

typedef __bf16 bf16;
typedef bf16 bf16x8 __attribute__((ext_vector_type(8)));
typedef float f32x4 __attribute__((ext_vector_type(4)));

#define LD 1024
#define BM 128
#define BN 64
#define BK 64
#define NKS (LD / BK)   // 16 K-steps

struct Job {
  const bf16 *Ah, *Al, *Bh, *Bl;   // A row-major [m][k], B transposed [n][k]
  const float *C1, *C2;            // optional fp32 addends (output layout)
  float *Of;                       // optional fp32 output
  bf16 *Orh, *Orl;                 // optional bf16 hi/lo row-major (A-form)
  bf16 *Oth, *Otl;                 // optional bf16 hi/lo transposed (B-form)
};

__device__ __forceinline__ f32x4 mfma16(bf16x8 a, bf16x8 b, f32x4 c) {
  return __builtin_amdgcn_mfma_f32_16x16x32_bf16(a, b, c, 0, 0, 0);
}

__global__ __launch_bounds__(256) void gemm_k(Job j0, Job j1)
{
  // Linear [row][64] bf16 tiles, XOR-swizzled at 16B-granule level:
  // granule_slot = (k>>3) ^ (row&7).  Rows are 128B so unswizzled reads
  // would be 32-way conflicts; swizzled phases cover all banks uniformly.
  __shared__ bf16 sA[2][2][BM * BK];   // [dbuf][hi/lo]  64 KiB
  __shared__ bf16 sB[2][2][BN * BK];   //                32 KiB

  const Job J = blockIdx.z ? j1 : j0;

  const int tid  = threadIdx.x;
  const int lane = tid & 63;
  const int wave = tid >> 6;

  // 2D XCD swizzle: XCD x=(id&7) -> (xr,xc)=(x>>2,x&3) owns a 4bm x 4bn block
  const int id  = blockIdx.y * 16 + blockIdx.x;
  const int xcd = id & 7, loc = id >> 3;
  const int bm = (((xcd >> 2) << 2) + (loc & 3)) * BM;   // 8 bm tiles
  const int bn = (((xcd & 3) << 2) + (loc >> 2)) * BN;   // 16 bn tiles

  // staging: A 128x64 (32 elem/thr per h/l), B 64x64 (16 elem/thr per h/l)
  const int ar = tid >> 1;
  const int br = tid >> 2;
  const bf16* gAh = J.Ah + (size_t)(bm + ar) * LD + (tid & 1) * 32;
  const bf16* gAl = J.Al + (size_t)(bm + ar) * LD + (tid & 1) * 32;
  const bf16* gBh = J.Bh + (size_t)(bn + br) * LD + (tid & 3) * 16;
  const bf16* gBl = J.Bl + (size_t)(bn + br) * LD + (tid & 3) * 16;

  // swizzled LDS write addresses (element units)
  int aw[4], bw[2];
#pragma unroll
  for (int q = 0; q < 4; ++q)
    aw[q] = ar * BK + ((((tid & 1) * 4 + q) ^ (ar & 7)) << 3);
#pragma unroll
  for (int q = 0; q < 2; ++q)
    bw[q] = br * BK + ((((tid & 3) * 2 + q) ^ (br & 7)) << 3);

  bf16x8 ra[2][4], rb[2][2];

  auto load_tile = [&](int kt) {
    const int o = kt * BK;
#pragma unroll
    for (int q = 0; q < 4; ++q) {
      ra[0][q] = *(const bf16x8*)(gAh + o + q * 8);
      ra[1][q] = *(const bf16x8*)(gAl + o + q * 8);
    }
#pragma unroll
    for (int q = 0; q < 2; ++q) {
      rb[0][q] = *(const bf16x8*)(gBh + o + q * 8);
      rb[1][q] = *(const bf16x8*)(gBl + o + q * 8);
    }
  };
  auto store_tile = [&](int buf) {
#pragma unroll
    for (int q = 0; q < 4; ++q) {
      *(bf16x8*)&sA[buf][0][aw[q]] = ra[0][q];
      *(bf16x8*)&sA[buf][1][aw[q]] = ra[1][q];
    }
#pragma unroll
    for (int q = 0; q < 2; ++q) {
      *(bf16x8*)&sB[buf][0][bw[q]] = rb[0][q];
      *(bf16x8*)&sB[buf][1][bw[q]] = rb[1][q];
    }
  };

  // wave -> 64x32 output tile = 4x2 grid of 16x16 MFMA tiles
  const int wm  = wave >> 1;          // 0..1
  const int wn  = wave & 1;           // 0..1
  const int l15 = lane & 15;
  const int l4  = lane >> 4;          // 0..3 (k granule within chunk)
  const int r7  = l15 & 7;            // XOR mask (row&7 == l15&7, tiles 16-aligned)

  int cs[2];                          // swizzled k-chunk column offsets
#pragma unroll
  for (int c = 0; c < 2; ++c) cs[c] = ((c * 4 + l4) ^ r7) << 3;
  int amo[4], bno[2];
#pragma unroll
  for (int mi = 0; mi < 4; ++mi) amo[mi] = (wm * 64 + mi * 16 + l15) * BK;
#pragma unroll
  for (int nj = 0; nj < 2; ++nj) bno[nj] = (wn * 32 + nj * 16 + l15) * BK;

  f32x4 acc[4][2];
#pragma unroll
  for (int mi = 0; mi < 4; ++mi)
#pragma unroll
    for (int nj = 0; nj < 2; ++nj) acc[mi][nj] = f32x4{0, 0, 0, 0};

  auto compute = [&](int buf) {
#pragma unroll
    for (int c = 0; c < 2; ++c) {           // two k=32 chunks
      bf16x8 a[4][2], b[2][2];
#pragma unroll
      for (int mi = 0; mi < 4; ++mi) {
        a[mi][0] = *(const bf16x8*)&sA[buf][0][amo[mi] + cs[c]];
        a[mi][1] = *(const bf16x8*)&sA[buf][1][amo[mi] + cs[c]];
      }
#pragma unroll
      for (int nj = 0; nj < 2; ++nj) {
        b[nj][0] = *(const bf16x8*)&sB[buf][0][bno[nj] + cs[c]];
        b[nj][1] = *(const bf16x8*)&sB[buf][1][bno[nj] + cs[c]];
      }
      // bf16x3: hi*hi + hi*lo + lo*hi
#pragma unroll
      for (int mi = 0; mi < 4; ++mi)
#pragma unroll
        for (int nj = 0; nj < 2; ++nj) {
          acc[mi][nj] = mfma16(a[mi][0], b[nj][0], acc[mi][nj]);
          acc[mi][nj] = mfma16(a[mi][0], b[nj][1], acc[mi][nj]);
          acc[mi][nj] = mfma16(a[mi][1], b[nj][0], acc[mi][nj]);
        }
    }
  };

  load_tile(0);
  store_tile(0);
  __syncthreads();
  int buf = 0;
  for (int kt = 0; kt < NKS; ++kt) {
    if (kt + 1 < NKS) load_tile(kt + 1);   // issue next-tile loads early
    compute(buf);
    if (kt + 1 < NKS) store_tile(buf ^ 1); // implicit vmcnt wait here
    __syncthreads();
    buf ^= 1;
  }
  // all waves past final barrier: LDS reusable as per-wave epilogue scratch

  // C/D layout (16x16x32): row = l4*4 + r, col = l15  [m89/m91 verified]
  float v[4][2][4];
#pragma unroll
  for (int mi = 0; mi < 4; ++mi)
#pragma unroll
    for (int nj = 0; nj < 2; ++nj) {
      const int gr = bm + wm * 64 + mi * 16 + l4 * 4;
      const int gc = bn + wn * 32 + nj * 16 + l15;
#pragma unroll
      for (int r = 0; r < 4; ++r) {
        float x = acc[mi][nj][r];
        if (J.C1) x += J.C1[(size_t)(gr + r) * LD + gc];
        if (J.C2) x += J.C2[(size_t)(gr + r) * LD + gc];
        v[mi][nj][r] = x;
      }
    }

  if (J.Of) {
#pragma unroll
    for (int mi = 0; mi < 4; ++mi)
#pragma unroll
      for (int nj = 0; nj < 2; ++nj) {
        const int gr = bm + wm * 64 + mi * 16 + l4 * 4;
        const int gc = bn + wn * 32 + nj * 16 + l15;
#pragma unroll
        for (int r = 0; r < 4; ++r)
          J.Of[(size_t)(gr + r) * LD + gc] = v[mi][nj][r];
      }
  }
  if (J.Orh) {
#pragma unroll
    for (int mi = 0; mi < 4; ++mi)
#pragma unroll
      for (int nj = 0; nj < 2; ++nj) {
        const int gr = bm + wm * 64 + mi * 16 + l4 * 4;
        const int gc = bn + wn * 32 + nj * 16 + l15;
#pragma unroll
        for (int r = 0; r < 4; ++r) {
          float x = v[mi][nj][r];
          bf16 h  = (bf16)x;
          bf16 lo = (bf16)(x - (float)h);
          size_t idx = (size_t)(gr + r) * LD + gc;
          J.Orh[idx] = h;
          J.Orl[idx] = lo;
        }
      }
  }
  if (J.Oth) {
    // per-wave 64x33 f32 scratch in sA (8448 B/wave, disjoint regions)
    float* scr = ((float*)&sA[0][0][0]) + wave * (64 * 33);
#pragma unroll
    for (int mi = 0; mi < 4; ++mi)
#pragma unroll
      for (int nj = 0; nj < 2; ++nj)
#pragma unroll
        for (int r = 0; r < 4; ++r)
          scr[(mi * 16 + l4 * 4 + r) * 33 + nj * 16 + l15] = v[mi][nj][r];
    const int n  = lane & 31;          // local out col
    const int mh = lane >> 5;          // m half (0/1)
    float tv[32];
#pragma unroll
    for (int j = 0; j < 32; ++j) tv[j] = scr[(mh * 32 + j) * 33 + n];
    bf16x8 th[4], tl2[4];
#pragma unroll
    for (int j = 0; j < 32; ++j) {
      bf16 h  = (bf16)tv[j];
      bf16 lo = (bf16)(tv[j] - (float)h);
      th[j >> 3][j & 7]  = h;
      tl2[j >> 3][j & 7] = lo;
    }
    bf16* ph = J.Oth + (size_t)(bn + wn * 32 + n) * LD + bm + wm * 64 + mh * 32;
    bf16* pl = J.Otl + (size_t)(bn + wn * 32 + n) * LD + bm + wm * 64 + mh * 32;
#pragma unroll
    for (int q = 0; q < 4; ++q) {
      *(bf16x8*)(ph + q * 8) = th[q];
      *(bf16x8*)(pl + q * 8) = tl2[q];
    }
  }
}

// One-time split/transpose of the fp32 inputs into A-form and B-form bf16.
__global__ __launch_bounds__(256) void prep_k(
    const float* __restrict__ t1, const float* __restrict__ t2,
    bf16* __restrict__ Ah1, bf16* __restrict__ Al1,
    bf16* __restrict__ Bh1, bf16* __restrict__ Bl1,
    bf16* __restrict__ Ah2, bf16* __restrict__ Al2,
    bf16* __restrict__ Bh2, bf16* __restrict__ Bl2)
{
  __shared__ float tl[64 * 65];
  const int z = blockIdx.z;
  const float* src = z ? t2 : t1;
  bf16* Ah = z ? Ah2 : Ah1;
  bf16* Al = z ? Al2 : Al1;
  bf16* Bh = z ? Bh2 : Bh1;
  bf16* Bl = z ? Bl2 : Bl1;

  const int tid = threadIdx.x;
  const int r0 = blockIdx.y * 64, c0 = blockIdx.x * 64;
  const int r  = tid >> 2;
  const int cc = (tid & 3) * 16;

  float vv[16];
#pragma unroll
  for (int q = 0; q < 4; ++q) {
    float4 x = *(const float4*)&src[(size_t)(r0 + r) * LD + c0 + cc + q * 4];
    vv[q * 4 + 0] = x.x; vv[q * 4 + 1] = x.y;
    vv[q * 4 + 2] = x.z; vv[q * 4 + 3] = x.w;
  }
  bf16x8 h8[2], l8[2];
#pragma unroll
  for (int j = 0; j < 16; ++j) {
    bf16 h  = (bf16)vv[j];
    bf16 lo = (bf16)(vv[j] - (float)h);
    h8[j >> 3][j & 7] = h;
    l8[j >> 3][j & 7] = lo;
    tl[r * 65 + cc + j] = vv[j];
  }
  {
    bf16* p = Ah + (size_t)(r0 + r) * LD + c0 + cc;
    *(bf16x8*)p = h8[0]; *(bf16x8*)(p + 8) = h8[1];
    bf16* q = Al + (size_t)(r0 + r) * LD + c0 + cc;
    *(bf16x8*)q = l8[0]; *(bf16x8*)(q + 8) = l8[1];
  }
  __syncthreads();
  float tv[16];
#pragma unroll
  for (int j = 0; j < 16; ++j) tv[j] = tl[(cc + j) * 65 + r];
#pragma unroll
  for (int j = 0; j < 16; ++j) {
    bf16 h  = (bf16)tv[j];
    bf16 lo = (bf16)(tv[j] - (float)h);
    h8[j >> 3][j & 7] = h;
    l8[j >> 3][j & 7] = lo;
  }
  {
    bf16* p = Bh + (size_t)(c0 + r) * LD + r0 + cc;
    *(bf16x8*)p = h8[0]; *(bf16x8*)(p + 8) = h8[1];
    bf16* q = Bl + (size_t)(c0 + r) * LD + r0 + cc;
    *(bf16x8*)q = l8[0]; *(bf16x8*)(q + 8) = l8[1];
  }
}

extern "C" void kernel_launch(void* const* d_in, const int* in_sizes, int n_in,
                              void* d_out, int out_size, void* d_ws, size_t ws_size,
                              hipStream_t stream) {
  (void)in_sizes; (void)n_in; (void)out_size;
  const float* t1 = (const float*)d_in[0];
  const float* t2 = (const float*)d_in[1];
  float* X = (float*)d_out;

  const size_t F32B = (size_t)LD * LD * 4;   // 4 MB
  const size_t B16B = (size_t)LD * LD * 2;   // 2 MB
  if (ws_size < F32B + 22 * B16B) return;    // 48 MB scratch

  char* p = (char*)d_ws;
  float* S = (float*)p; p += F32B;
  bf16 *Wh[11], *Wl[11];
  for (int i = 0; i < 11; ++i) {
    Wh[i] = (bf16*)p; p += B16B;
    Wl[i] = (bf16*)p; p += B16B;
  }
  // W0: t1A -> X2B      W1: t1B -> S2B/S8B -> P48B   W2: t2A   W3: t2B
  // W4: SB0 (S1/S4/S16) W5,W6: P2/P8/P32 A,B         W7,W8: P4/P16 A,B
  // W9: T (doubling) -> P48A                         W10: Tx/T2/T3

  auto job = [](const bf16* ah, const bf16* al, const bf16* bh, const bf16* bl,
                const float* c1, const float* c2, float* of,
                bf16* orh, bf16* orl, bf16* oth, bf16* otl) -> Job {
    return Job{ah, al, bh, bl, c1, c2, of, orh, orl, oth, otl};
  };
  auto L2j = [&](Job a, Job b) {
    gemm_k<<<dim3(16, 8, 2), 256, 0, stream>>>(a, b);
  };
  auto L1j = [&](Job a) {
    gemm_k<<<dim3(16, 8, 1), 256, 0, stream>>>(a, a);
  };

  prep_k<<<dim3(16, 16, 2), 256, 0, stream>>>(t1, t2,
      Wh[0], Wl[0], Wh[1], Wl[1], Wh[2], Wl[2], Wh[3], Wl[3]);

  // L1: S1 = t1 + t1@t2 -> S,SB0 | P2 = t2@t2 -> W5(A),W6(B)
  L2j(job(Wh[0],Wl[0], Wh[3],Wl[3], t1,nullptr, S, nullptr,nullptr, Wh[4],Wl[4]),
      job(Wh[2],Wl[2], Wh[3],Wl[3], nullptr,nullptr, nullptr, Wh[5],Wl[5], Wh[6],Wl[6]));
  // L2: T1 = t2@S1B -> W9 | Tx = P2@t1B -> W10
  L2j(job(Wh[2],Wl[2], Wh[4],Wl[4], nullptr,nullptr, nullptr, Wh[9],Wl[9], nullptr,nullptr),
      job(Wh[5],Wl[5], Wh[1],Wl[1], nullptr,nullptr, nullptr, Wh[10],Wl[10], nullptr,nullptr));
  // L3: S2 = S + T1@t2B -> S, S2B(W1)
  L1j(job(Wh[9],Wl[9], Wh[3],Wl[3], S,nullptr, S, nullptr,nullptr, Wh[1],Wl[1]));
  // L4: T = P2@S2B -> W9 | X2 = S2 + Tx@P2B -> X2B(W0)
  L2j(job(Wh[5],Wl[5], Wh[1],Wl[1], nullptr,nullptr, nullptr, Wh[9],Wl[9], nullptr,nullptr),
      job(Wh[10],Wl[10], Wh[6],Wl[6], S,nullptr, nullptr, nullptr,nullptr, Wh[0],Wl[0]));
  // L5: S4 = S + T@P2B -> S, SB0(W4) | P4 = P2@P2B -> W7(A),W8(B)
  L2j(job(Wh[9],Wl[9], Wh[6],Wl[6], S,nullptr, S, nullptr,nullptr, Wh[4],Wl[4]),
      job(Wh[5],Wl[5], Wh[6],Wl[6], nullptr,nullptr, nullptr, Wh[7],Wl[7], Wh[8],Wl[8]));
  // L6: T = P4@S4B -> W9
  L1j(job(Wh[7],Wl[7], Wh[4],Wl[4], nullptr,nullptr, nullptr, Wh[9],Wl[9], nullptr,nullptr));
  // L7: S8 = S + T@P4B -> S, S8B(W1) | P8 = P4@P4B -> W5(A),W6(B)
  L2j(job(Wh[9],Wl[9], Wh[8],Wl[8], S,nullptr, S, nullptr,nullptr, Wh[1],Wl[1]),
      job(Wh[7],Wl[7], Wh[8],Wl[8], nullptr,nullptr, nullptr, Wh[5],Wl[5], Wh[6],Wl[6]));
  // L8: T = P8@S8B -> W9
  L1j(job(Wh[5],Wl[5], Wh[1],Wl[1], nullptr,nullptr, nullptr, Wh[9],Wl[9], nullptr,nullptr));
  // L9: S16 = S + T@P8B -> S, SB0(W4) | P16 = P8@P8B -> W7(A),W8(B)
  L2j(job(Wh[9],Wl[9], Wh[6],Wl[6], S,nullptr, S, nullptr,nullptr, Wh[4],Wl[4]),
      job(Wh[5],Wl[5], Wh[6],Wl[6], nullptr,nullptr, nullptr, Wh[7],Wl[7], Wh[8],Wl[8]));
  // La: T = P16@S16B -> W9 | P32 = P16@P16B -> W5(A),W6(B)
  L2j(job(Wh[7],Wl[7], Wh[4],Wl[4], nullptr,nullptr, nullptr, Wh[9],Wl[9], nullptr,nullptr),
      job(Wh[7],Wl[7], Wh[8],Wl[8], nullptr,nullptr, nullptr, Wh[5],Wl[5], Wh[6],Wl[6]));
  // Lb: S32 = S + T@P16B -> S | T2 = P32@S16B -> W10
  L2j(job(Wh[9],Wl[9], Wh[8],Wl[8], S,nullptr, S, nullptr,nullptr, nullptr,nullptr),
      job(Wh[5],Wl[5], Wh[4],Wl[4], nullptr,nullptr, nullptr, Wh[10],Wl[10], nullptr,nullptr));
  // Lc: S48 = S + T2@P32B -> S | P48 = P16@P32B -> W9(A), W1(B)
  L2j(job(Wh[10],Wl[10], Wh[6],Wl[6], S,nullptr, S, nullptr,nullptr, nullptr,nullptr),
      job(Wh[7],Wl[7], Wh[6],Wl[6], nullptr,nullptr, nullptr, Wh[9],Wl[9], Wh[1],Wl[1]));
  // Ld: T3 = P48@X2B -> W10
  L1j(job(Wh[9],Wl[9], Wh[0],Wl[0], nullptr,nullptr, nullptr, Wh[10],Wl[10], nullptr,nullptr));
  // Le: out = S48 + t1 + T3@P48B -> d_out
  L1j(job(Wh[10],Wl[10], Wh[1],Wl[1], S,t1, X, nullptr,nullptr, nullptr,nullptr));
}